// Round 1
// baseline (1284.893 us; speedup 1.0000x reference)
//
#include <hip/hip_runtime.h>

#define N_NODES 70000
#define N_EDGES 800000
#define ROWLEN  1044
#define KDIM    1024
#define FEAT    128
#define NOUT    256      // stacked [y_l | y_r]
#define HIDDEN  37
#define CIN     148

typedef __attribute__((ext_vector_type(8))) short short8;
typedef __attribute__((ext_vector_type(4))) float f32x4;

static __device__ __forceinline__ unsigned short f2bf(float f) {
  unsigned int u = __float_as_uint(f);
  u += 0x7FFF + ((u >> 16) & 1);          // RNE
  return (unsigned short)(u >> 16);
}
static __device__ __forceinline__ float bf2f(unsigned int u) {
  return __uint_as_float(u << 16);
}

// ---- W (2 x 128 x 1024 fp32) -> bf16, stacked [Wl; Wr] ----------------------
__global__ __launch_bounds__(256) void cvt_w(
    const float* __restrict__ wl, const float* __restrict__ wr,
    unsigned short* __restrict__ wbf)
{
  const int i = blockIdx.x * 256 + threadIdx.x;   // float4 index, 0..65535
  const int half = (FEAT * KDIM) / 4;             // 32768
  const float* src = (i < half) ? wl : wr;
  const int j = (i < half) ? i : (i - half);
  const float4 v = ((const float4*)src)[j];
  ushort4 u = make_ushort4(f2bf(v.x), f2bf(v.y), f2bf(v.z), f2bf(v.w));
  ((ushort4*)wbf)[i] = u;
}

// ---- y[m, 0:256] = feat[m, 0:1024] @ [Wl;Wr]^T  (bf16 MFMA, 128x128 tile) ---
__global__ __launch_bounds__(256) void gemm_sage(
    const float* __restrict__ feat,
    const unsigned short* __restrict__ wbf,
    unsigned short* __restrict__ y)
{
  __shared__ __align__(16) unsigned short As[128][72];  // +8 pad: 144B stride
  __shared__ __align__(16) unsigned short Bs[128][72];

  const int tid  = threadIdx.x;
  const int lane = tid & 63;
  const int wid  = tid >> 6;
  const int wm   = (wid & 1) * 64;       // wave quadrant inside 128x128
  const int wn   = (wid >> 1) * 64;
  const int m0   = blockIdx.x * 128;
  const int nblk = blockIdx.y;           // 0 -> Wl, 1 -> Wr
  const unsigned short* wb = wbf + (size_t)nblk * 128 * KDIM;

  f32x4 acc[4][4];
  const f32x4 zero = {0.f, 0.f, 0.f, 0.f};
  #pragma unroll
  for (int i = 0; i < 4; i++)
    #pragma unroll
    for (int j = 0; j < 4; j++) acc[i][j] = zero;

  const int c4  = tid & 15;   // A col group (4 floats)
  const int r0  = tid >> 4;   // A row base
  const int c8  = tid & 7;    // B col group (8 bf16)
  const int r0b = tid >> 3;   // B row base

  for (int kk = 0; kk < KDIM; kk += 64) {
    // stage A: 128x64 fp32 -> bf16 (fused convert)
    #pragma unroll
    for (int i = 0; i < 8; i++) {
      int r = r0 + 16 * i;
      int m = m0 + r; if (m >= N_NODES) m = N_NODES - 1;   // clamp; not stored
      const float4 v = *(const float4*)(feat + (size_t)m * ROWLEN + kk + c4 * 4);
      ushort4 u = make_ushort4(f2bf(v.x), f2bf(v.y), f2bf(v.z), f2bf(v.w));
      *(ushort4*)&As[r][c4 * 4] = u;
    }
    // stage B: 128x64 bf16 (pre-converted, L2-resident)
    #pragma unroll
    for (int i = 0; i < 4; i++) {
      int r = r0b + 32 * i;
      const uint4 v = *(const uint4*)(wb + (size_t)r * KDIM + kk + c8 * 8);
      *(uint4*)&Bs[r][c8 * 8] = v;
    }
    __syncthreads();
    #pragma unroll
    for (int s = 0; s < 2; s++) {
      const int col = s * 32 + (lane >> 4) * 8;   // A/B frag: k = quad*8+j
      const int row = lane & 15;                  //          m/n = lane&15
      short8 a[4], b[4];
      #pragma unroll
      for (int t = 0; t < 4; t++) a[t] = *(const short8*)&As[wm + t * 16 + row][col];
      #pragma unroll
      for (int t = 0; t < 4; t++) b[t] = *(const short8*)&Bs[wn + t * 16 + row][col];
      #pragma unroll
      for (int i = 0; i < 4; i++)
        #pragma unroll
        for (int j = 0; j < 4; j++)
          acc[i][j] = __builtin_amdgcn_mfma_f32_16x16x32_bf16(a[i], b[j], acc[i][j], 0, 0, 0);
    }
    __syncthreads();
  }

  // C/D layout: n = lane&15, m = (lane>>4)*4 + reg   [m89-verified]
  const int mb = m0 + wm + (lane >> 4) * 4;
  const int nb = nblk * 128 + wn + (lane & 15);
  #pragma unroll
  for (int i = 0; i < 4; i++) {
    #pragma unroll
    for (int r = 0; r < 4; r++) {
      const int m = mb + i * 16 + r;
      if (m < N_NODES) {
        #pragma unroll
        for (int j = 0; j < 4; j++)
          y[(size_t)m * NOUT + nb + j * 16] = f2bf(acc[i][j][r]);
      }
    }
  }
}

// ---- agg[dst] += y_l[src] (post-projection aggregation), cnt[dst]++ ---------
__global__ __launch_bounds__(256) void scatter_edges(
    const int* __restrict__ edges,
    const unsigned short* __restrict__ y,
    float* __restrict__ agg,
    unsigned int* __restrict__ cnt)
{
  const int e    = (int)((blockIdx.x * 256u + threadIdx.x) >> 6);  // 1 wave/edge
  const int lane = threadIdx.x & 63;
  if (e >= N_EDGES) return;
  const int src = edges[e];
  const int dst = edges[N_EDGES + e];
  const unsigned int v = *(const unsigned int*)(y + (size_t)src * NOUT + lane * 2);
  float* ad = agg + (size_t)dst * FEAT;
  atomicAdd(ad + lane * 2,     bf2f(v & 0xFFFFu));
  atomicAdd(ad + lane * 2 + 1, bf2f(v >> 16));
  if (lane == 0) atomicAdd(cnt + dst, 1u);
}

// ---- per-node: sage-relu + concat -> fc1 -> relu -> BN -> fc2 ---------------
__global__ __launch_bounds__(256) void epilogue(
    const float* __restrict__ feat,
    const unsigned short* __restrict__ y,
    const float* __restrict__ agg,
    const unsigned int* __restrict__ cnt,
    const float* __restrict__ b_sage_l,
    const float* __restrict__ fc1_w, const float* __restrict__ fc1_b,
    const float* __restrict__ fc2_w, const float* __restrict__ fc2_b,
    const float* __restrict__ bn_gamma, const float* __restrict__ bn_beta,
    const float* __restrict__ bn_mean, const float* __restrict__ bn_var,
    float* __restrict__ out)
{
  __shared__ float w1t[CIN][HIDDEN + 1];  // fc1_w transposed: conflict-free j-reads
  __shared__ float vbuf[4][CIN];
  __shared__ float hbuf[4][HIDDEN + 3];
  const int tid  = threadIdx.x;
  const int lane = tid & 63;
  const int w    = tid >> 6;

  for (int i = tid; i < HIDDEN * CIN; i += 256) {
    const int j = i / CIN;
    const int c = i - j * CIN;
    w1t[c][j] = fc1_w[i];
  }
  __syncthreads();

  const int m = blockIdx.x * 4 + w;       // 70000 = 17500*4, no guard needed
  const float inv = 1.0f / fmaxf((float)cnt[m], 1.0f);
  const float* aggm = agg + (size_t)m * FEAT;
  const unsigned short* ym = y + (size_t)m * NOUT + FEAT;   // y_r half

  for (int c = lane; c < CIN; c += 64) {
    float v;
    if (c < FEAT)
      v = fmaxf(aggm[c] * inv + b_sage_l[c] + bf2f(ym[c]), 0.0f);  // relu(sage)
    else
      v = feat[(size_t)m * ROWLEN + KDIM + (c - FEAT)];            // extra 20 (no relu)
    vbuf[w][c] = v;
  }
  __syncthreads();

  if (lane < HIDDEN) {
    float h = fc1_b[lane];
    #pragma unroll 4
    for (int c = 0; c < CIN; c++) h += w1t[c][lane] * vbuf[w][c];
    h = fmaxf(h, 0.0f);
    h = (h - bn_mean[lane]) * rsqrtf(bn_var[lane] + 1e-5f) * bn_gamma[lane] + bn_beta[lane];
    hbuf[w][lane] = h;
  }
  __syncthreads();

  if (lane < 3) {
    float o = fc2_b[lane];
    #pragma unroll
    for (int j = 0; j < HIDDEN; j++) o += fc2_w[lane * HIDDEN + j] * hbuf[w][j];
    out[(size_t)m * 3 + lane] = o;
  }
}

// ---- workspace layout (72.5 MB total) ---------------------------------------
#define AGG_OFF 0u
#define AGG_BYTES (N_NODES * FEAT * 4u)            // 35,840,000
#define CNT_OFF AGG_BYTES                          // 35,840,000
#define CNT_BYTES (N_NODES * 4u)                   //    280,000
#define Y_OFF   (CNT_OFF + CNT_BYTES)              // 36,120,000 (16-aligned)
#define Y_BYTES (N_NODES * NOUT * 2u)              // 35,840,000
#define WBF_OFF (Y_OFF + Y_BYTES)                  // 71,960,000 (16-aligned)

extern "C" void kernel_launch(void* const* d_in, const int* in_sizes, int n_in,
                              void* d_out, int out_size, void* d_ws, size_t ws_size,
                              hipStream_t stream) {
  const float* feat     = (const float*)d_in[0];
  const int*   edges    = (const int*)  d_in[1];
  // d_in[2] (edges2), d_in[3] (edge_features): unused by the reference
  const float* w_sage_l = (const float*)d_in[4];
  const float* b_sage_l = (const float*)d_in[5];
  const float* w_sage_r = (const float*)d_in[6];
  const float* fc1_w    = (const float*)d_in[7];
  const float* fc1_b    = (const float*)d_in[8];
  const float* fc2_w    = (const float*)d_in[9];
  const float* fc2_b    = (const float*)d_in[10];
  const float* bn_gamma = (const float*)d_in[11];
  const float* bn_beta  = (const float*)d_in[12];
  const float* bn_mean  = (const float*)d_in[13];
  const float* bn_var   = (const float*)d_in[14];
  float* out = (float*)d_out;

  char* ws = (char*)d_ws;
  float*          agg = (float*)(ws + AGG_OFF);
  unsigned int*   cnt = (unsigned int*)(ws + CNT_OFF);
  unsigned short* y   = (unsigned short*)(ws + Y_OFF);
  unsigned short* wbf = (unsigned short*)(ws + WBF_OFF);

  (void)hipMemsetAsync(ws, 0, AGG_BYTES + CNT_BYTES, stream);  // zero agg + cnt
  cvt_w<<<256, 256, 0, stream>>>(w_sage_l, w_sage_r, wbf);
  dim3 gg((N_NODES + 127) / 128, 2);
  gemm_sage<<<gg, 256, 0, stream>>>(feat, wbf, y);
  scatter_edges<<<N_EDGES / 4, 256, 0, stream>>>(edges, y, agg, cnt);
  epilogue<<<N_NODES / 4, 256, 0, stream>>>(feat, y, agg, cnt, b_sage_l,
                                            fc1_w, fc1_b, fc2_w, fc2_b,
                                            bn_gamma, bn_beta, bn_mean, bn_var, out);
}

// Round 2
// 697.086 us; speedup vs baseline: 1.8432x; 1.8432x over previous
//
#include <hip/hip_runtime.h>

#define N_NODES 70000
#define N_EDGES 800000
#define ROWLEN  1044
#define KDIM    1024
#define FEAT    128
#define NOUT    256      // stacked [y_l | y_r]
#define HIDDEN  37
#define CIN     148
#define NCHUNK  69       // ceil(70000/1024)

typedef __attribute__((ext_vector_type(8))) short short8;
typedef __attribute__((ext_vector_type(4))) float f32x4;

static __device__ __forceinline__ unsigned short f2bf(float f) {
  unsigned int u = __float_as_uint(f);
  u += 0x7FFF + ((u >> 16) & 1);          // RNE
  return (unsigned short)(u >> 16);
}
static __device__ __forceinline__ float bf2f(unsigned int u) {
  return __uint_as_float(u << 16);
}

// ---- W (2 x 128 x 1024 fp32) -> bf16, stacked [Wl; Wr] ----------------------
__global__ __launch_bounds__(256) void cvt_w(
    const float* __restrict__ wl, const float* __restrict__ wr,
    unsigned short* __restrict__ wbf)
{
  const int i = blockIdx.x * 256 + threadIdx.x;   // float4 index, 0..65535
  const int half = (FEAT * KDIM) / 4;             // 32768
  const float* src = (i < half) ? wl : wr;
  const int j = (i < half) ? i : (i - half);
  const float4 v = ((const float4*)src)[j];
  ushort4 u = make_ushort4(f2bf(v.x), f2bf(v.y), f2bf(v.z), f2bf(v.w));
  ((ushort4*)wbf)[i] = u;
}

// ---- CSR build: histogram of dst --------------------------------------------
__global__ __launch_bounds__(256) void hist(
    const int* __restrict__ edges, unsigned int* __restrict__ cnt)
{
  const int e = blockIdx.x * 256 + threadIdx.x;   // grid = 3125 exact
  atomicAdd(&cnt[edges[N_EDGES + e]], 1u);
}

// ---- scan stage A: per-1024-chunk sums --------------------------------------
__global__ __launch_bounds__(256) void scan_a(
    const unsigned int* __restrict__ cnt, unsigned int* __restrict__ partial)
{
  __shared__ unsigned int s[256];
  const int t = threadIdx.x;
  const int base = blockIdx.x * 1024 + t * 4;
  unsigned int sum = 0;
  #pragma unroll
  for (int j = 0; j < 4; j++) sum += (base + j < N_NODES) ? cnt[base + j] : 0u;
  s[t] = sum; __syncthreads();
  for (int off = 128; off > 0; off >>= 1) {
    if (t < off) s[t] += s[t + off];
    __syncthreads();
  }
  if (t == 0) partial[blockIdx.x] = s[0];
}

// ---- scan stage B: exclusive scan of 69 chunk sums (1 block) ----------------
__global__ __launch_bounds__(128) void scan_b(
    const unsigned int* __restrict__ partial, unsigned int* __restrict__ chunk_off)
{
  __shared__ unsigned int s[128];
  const int t = threadIdx.x;
  const unsigned int own = (t < NCHUNK) ? partial[t] : 0u;
  s[t] = own; __syncthreads();
  for (int off = 1; off < 128; off <<= 1) {
    unsigned int x = (t >= off) ? s[t - off] : 0u;
    __syncthreads();
    s[t] += x;
    __syncthreads();
  }
  if (t < NCHUNK) chunk_off[t] = s[t] - own;
}

// ---- scan stage C: row_start = chunk_off + in-chunk exclusive scan ----------
__global__ __launch_bounds__(256) void scan_c(
    const unsigned int* __restrict__ cnt, const unsigned int* __restrict__ chunk_off,
    unsigned int* __restrict__ row_start)
{
  __shared__ unsigned int s[256];
  const int t = threadIdx.x;
  const int base = blockIdx.x * 1024 + t * 4;
  unsigned int v[4], sum = 0;
  #pragma unroll
  for (int j = 0; j < 4; j++) { v[j] = (base + j < N_NODES) ? cnt[base + j] : 0u; sum += v[j]; }
  s[t] = sum; __syncthreads();
  for (int off = 1; off < 256; off <<= 1) {      // Hillis-Steele inclusive
    unsigned int x = (t >= off) ? s[t - off] : 0u;
    __syncthreads();
    s[t] += x;
    __syncthreads();
  }
  unsigned int run = chunk_off[blockIdx.x] + (s[t] - sum);
  #pragma unroll
  for (int j = 0; j < 4; j++) {
    if (base + j < N_NODES) row_start[base + j] = run;
    run += v[j];
  }
}

// ---- CSR fill: col[row_start[dst] + slot] = src ------------------------------
__global__ __launch_bounds__(256) void fill_csr(
    const int* __restrict__ edges, const unsigned int* __restrict__ row_start,
    unsigned int* __restrict__ wc, int* __restrict__ col)
{
  const int e = blockIdx.x * 256 + threadIdx.x;   // grid = 3125 exact
  const int src = edges[e];
  const int dst = edges[N_EDGES + e];
  const unsigned int pos = row_start[dst] + atomicAdd(&wc[dst], 1u);
  col[pos] = src;
}

// ---- y[m, 0:256] = feat[m, 0:1024] @ [Wl;Wr]^T (bf16 MFMA, 128x256 tile) ----
__global__ __launch_bounds__(256, 2) void gemm_sage(
    const float* __restrict__ feat,
    const unsigned short* __restrict__ wbf,
    unsigned short* __restrict__ y)
{
  __shared__ __align__(16) unsigned short As[128][72];  // +8 pad: 144B stride
  __shared__ __align__(16) unsigned short Bs[256][72];

  const int tid  = threadIdx.x;
  const int lane = tid & 63;
  const int wid  = tid >> 6;
  const int wm   = (wid & 1) * 64;       // wave tile: 64 x 128
  const int wn   = (wid >> 1) * 128;
  const int m0   = blockIdx.x * 128;

  f32x4 acc[4][8];
  const f32x4 zero = {0.f, 0.f, 0.f, 0.f};
  #pragma unroll
  for (int i = 0; i < 4; i++)
    #pragma unroll
    for (int j = 0; j < 8; j++) acc[i][j] = zero;

  const int c4  = tid & 15;   // A col group (4 floats)
  const int r0  = tid >> 4;   // A row base
  const int c8  = tid & 7;    // B col group (8 bf16)
  const int r0b = tid >> 3;   // B row base

  for (int kk = 0; kk < KDIM; kk += 64) {
    // stage A: 128x64 fp32 -> bf16 (fused convert)
    #pragma unroll
    for (int i = 0; i < 8; i++) {
      int r = r0 + 16 * i;
      int m = m0 + r; if (m >= N_NODES) m = N_NODES - 1;   // clamp; not stored
      const float4 v = *(const float4*)(feat + (size_t)m * ROWLEN + kk + c4 * 4);
      ushort4 u = make_ushort4(f2bf(v.x), f2bf(v.y), f2bf(v.z), f2bf(v.w));
      *(ushort4*)&As[r][c4 * 4] = u;
    }
    // stage B: 256x64 bf16 (pre-converted, L2-resident)
    #pragma unroll
    for (int i = 0; i < 8; i++) {
      int r = r0b + 32 * i;
      const uint4 v = *(const uint4*)(wbf + (size_t)r * KDIM + kk + c8 * 8);
      *(uint4*)&Bs[r][c8 * 8] = v;
    }
    __syncthreads();
    #pragma unroll
    for (int s = 0; s < 2; s++) {
      const int colk = s * 32 + (lane >> 4) * 8;  // frag: k = quad*8+j
      const int row  = lane & 15;
      short8 a[4], b[8];
      #pragma unroll
      for (int t = 0; t < 4; t++) a[t] = *(const short8*)&As[wm + t * 16 + row][colk];
      #pragma unroll
      for (int t = 0; t < 8; t++) b[t] = *(const short8*)&Bs[wn + t * 16 + row][colk];
      #pragma unroll
      for (int i = 0; i < 4; i++)
        #pragma unroll
        for (int j = 0; j < 8; j++)
          acc[i][j] = __builtin_amdgcn_mfma_f32_16x16x32_bf16(a[i], b[j], acc[i][j], 0, 0, 0);
    }
    __syncthreads();
  }

  // C/D layout: n = lane&15, m = (lane>>4)*4 + reg   [m89-verified]
  const int mb = m0 + wm + (lane >> 4) * 4;
  const int nb = wn + (lane & 15);
  #pragma unroll
  for (int i = 0; i < 4; i++) {
    #pragma unroll
    for (int r = 0; r < 4; r++) {
      const int m = mb + i * 16 + r;
      if (m < N_NODES) {
        #pragma unroll
        for (int j = 0; j < 8; j++)
          y[(size_t)m * NOUT + nb + j * 16] = f2bf(acc[i][j][r]);
      }
    }
  }
}

// ---- fused: CSR gather mean + sage-relu + concat + fc1 + BN + fc2 -----------
__global__ __launch_bounds__(256) void gather_epilogue(
    const float* __restrict__ feat,
    const unsigned short* __restrict__ y,
    const unsigned int* __restrict__ row_start,
    const unsigned int* __restrict__ cnt,
    const int* __restrict__ col,
    const float* __restrict__ b_sage_l,
    const float* __restrict__ fc1_w, const float* __restrict__ fc1_b,
    const float* __restrict__ fc2_w, const float* __restrict__ fc2_b,
    const float* __restrict__ bn_gamma, const float* __restrict__ bn_beta,
    const float* __restrict__ bn_mean, const float* __restrict__ bn_var,
    float* __restrict__ out)
{
  __shared__ float w1t[CIN][HIDDEN + 1];  // fc1_w transposed: conflict-free j-reads
  __shared__ float vbuf[4][CIN];
  __shared__ float hbuf[4][HIDDEN + 3];
  const int tid  = threadIdx.x;
  const int lane = tid & 63;
  const int w    = tid >> 6;

  for (int i = tid; i < HIDDEN * CIN; i += 256) {
    const int j = i / CIN;
    const int c = i - j * CIN;
    w1t[c][j] = fc1_w[i];
  }
  __syncthreads();

  const int m = blockIdx.x * 4 + w;       // 70000 = 17500*4, no guard needed
  const int e0 = (int)row_start[m];
  const int n  = (int)cnt[m];

  // gather: sum of y_l[src] rows; lane covers channels 2*lane, 2*lane+1
  float s0 = 0.f, s1 = 0.f;
  int i = 0;
  for (; i + 2 <= n; i += 2) {            // 2 independent chains to hide latency
    const int sa = col[e0 + i];
    const int sb = col[e0 + i + 1];
    const unsigned int va = *(const unsigned int*)(y + (size_t)sa * NOUT + lane * 2);
    const unsigned int vb = *(const unsigned int*)(y + (size_t)sb * NOUT + lane * 2);
    s0 += bf2f(va & 0xFFFFu) + bf2f(vb & 0xFFFFu);
    s1 += bf2f(va >> 16)     + bf2f(vb >> 16);
  }
  if (i < n) {
    const int sa = col[e0 + i];
    const unsigned int va = *(const unsigned int*)(y + (size_t)sa * NOUT + lane * 2);
    s0 += bf2f(va & 0xFFFFu);
    s1 += bf2f(va >> 16);
  }

  const float inv = 1.0f / fmaxf((float)n, 1.0f);
  const unsigned int vr = *(const unsigned int*)(y + (size_t)m * NOUT + FEAT + lane * 2);
  vbuf[w][2 * lane]     = fmaxf(s0 * inv + b_sage_l[2 * lane]     + bf2f(vr & 0xFFFFu), 0.0f);
  vbuf[w][2 * lane + 1] = fmaxf(s1 * inv + b_sage_l[2 * lane + 1] + bf2f(vr >> 16),     0.0f);
  if (lane < CIN - FEAT)
    vbuf[w][FEAT + lane] = feat[(size_t)m * ROWLEN + KDIM + lane];  // extra 20 (no relu)
  __syncthreads();

  if (lane < HIDDEN) {
    float h = fc1_b[lane];
    #pragma unroll 4
    for (int c = 0; c < CIN; c++) h += w1t[c][lane] * vbuf[w][c];
    h = fmaxf(h, 0.0f);
    h = (h - bn_mean[lane]) * rsqrtf(bn_var[lane] + 1e-5f) * bn_gamma[lane] + bn_beta[lane];
    hbuf[w][lane] = h;
  }
  __syncthreads();

  if (lane < 3) {
    float o = fc2_b[lane];
    #pragma unroll
    for (int j = 0; j < HIDDEN; j++) o += fc2_w[lane * HIDDEN + j] * hbuf[w][j];
    out[(size_t)m * 3 + lane] = o;
  }
}

// ---- workspace layout (~40.4 MB) --------------------------------------------
#define Y_OFF    0u
#define Y_BYTES  (N_NODES * NOUT * 2u)            // 35,840,000
#define WBF_OFF  Y_BYTES                          // 35,840,000 (16-aligned)
#define WBF_BYTES (NOUT * KDIM * 2u)              //    524,288
#define CNT_OFF  (WBF_OFF + WBF_BYTES)            // 36,364,288 (16-aligned)
#define CNT_BYTES (N_NODES * 4u)                  //    280,000
#define WC_OFF   (CNT_OFF + CNT_BYTES)            // 36,644,288
#define RS_OFF   (WC_OFF + CNT_BYTES)             // 36,924,288
#define PART_OFF (RS_OFF + CNT_BYTES)             // 37,204,288
#define COFF_OFF (PART_OFF + 512u)                // 37,204,800
#define COL_OFF  (COFF_OFF + 512u)                // 37,205,312
#define COL_BYTES (N_EDGES * 4u)                  //  3,200,000

extern "C" void kernel_launch(void* const* d_in, const int* in_sizes, int n_in,
                              void* d_out, int out_size, void* d_ws, size_t ws_size,
                              hipStream_t stream) {
  const float* feat     = (const float*)d_in[0];
  const int*   edges    = (const int*)  d_in[1];
  // d_in[2] (edges2), d_in[3] (edge_features): unused by the reference
  const float* w_sage_l = (const float*)d_in[4];
  const float* b_sage_l = (const float*)d_in[5];
  const float* w_sage_r = (const float*)d_in[6];
  const float* fc1_w    = (const float*)d_in[7];
  const float* fc1_b    = (const float*)d_in[8];
  const float* fc2_w    = (const float*)d_in[9];
  const float* fc2_b    = (const float*)d_in[10];
  const float* bn_gamma = (const float*)d_in[11];
  const float* bn_beta  = (const float*)d_in[12];
  const float* bn_mean  = (const float*)d_in[13];
  const float* bn_var   = (const float*)d_in[14];
  float* out = (float*)d_out;

  char* ws = (char*)d_ws;
  unsigned short* y    = (unsigned short*)(ws + Y_OFF);
  unsigned short* wbf  = (unsigned short*)(ws + WBF_OFF);
  unsigned int*   cnt  = (unsigned int*)(ws + CNT_OFF);
  unsigned int*   wc   = (unsigned int*)(ws + WC_OFF);
  unsigned int*   rs   = (unsigned int*)(ws + RS_OFF);
  unsigned int*   part = (unsigned int*)(ws + PART_OFF);
  unsigned int*   coff = (unsigned int*)(ws + COFF_OFF);
  int*            col  = (int*)(ws + COL_OFF);

  (void)hipMemsetAsync(ws + CNT_OFF, 0, 2u * CNT_BYTES, stream);  // zero cnt + wc
  cvt_w<<<256, 256, 0, stream>>>(w_sage_l, w_sage_r, wbf);
  hist<<<N_EDGES / 256, 256, 0, stream>>>(edges, cnt);
  scan_a<<<NCHUNK, 256, 0, stream>>>(cnt, part);
  scan_b<<<1, 128, 0, stream>>>(part, coff);
  scan_c<<<NCHUNK, 256, 0, stream>>>(cnt, coff, rs);
  fill_csr<<<N_EDGES / 256, 256, 0, stream>>>(edges, rs, wc, col);
  gemm_sage<<<(N_NODES + 127) / 128, 256, 0, stream>>>(feat, wbf, y);
  gather_epilogue<<<N_NODES / 4, 256, 0, stream>>>(feat, y, rs, cnt, col, b_sage_l,
                                                   fc1_w, fc1_b, fc2_w, fc2_b,
                                                   bn_gamma, bn_beta, bn_mean, bn_var, out);
}

// Round 3
// 683.914 us; speedup vs baseline: 1.8787x; 1.0193x over previous
//
#include <hip/hip_runtime.h>
#include <hip/hip_bf16.h>

#define N_NODES 70000
#define N_EDGES 800000
#define ROWLEN  1044
#define KDIM    1024
#define FEAT    128
#define NOUT    256      // stacked [y_l | y_r]
#define HIDDEN  37
#define CIN     148
#define NCHUNK  69       // ceil(70000/1024)
#define TM      96       // gemm M-tile: 730 blocks, 3 blocks/CU -> single round

typedef __attribute__((ext_vector_type(8))) short short8;
typedef __attribute__((ext_vector_type(4))) float f32x4;

static __device__ __forceinline__ unsigned short f2bf(float f) {
  unsigned int u = __float_as_uint(f);
  u += 0x7FFF + ((u >> 16) & 1);          // RNE
  return (unsigned short)(u >> 16);
}
static __device__ __forceinline__ float bf2f(unsigned int u) {
  return __uint_as_float(u << 16);
}
static __device__ __forceinline__ unsigned int pk2bf(float a, float b) {
  union { __hip_bfloat162 h; unsigned int u; } cv;
  cv.h = __float22bfloat162_rn(float2{a, b});   // v_cvt_pk_bf16_f32
  return cv.u;
}

// ---- W -> bf16 (stacked [Wl; Wr]) + zero cnt/wc -----------------------------
__global__ __launch_bounds__(256) void cvt_w(
    const float* __restrict__ wl, const float* __restrict__ wr,
    unsigned short* __restrict__ wbf, unsigned int* __restrict__ z)
{
  const int i = blockIdx.x * 256 + threadIdx.x;   // float4 index, 0..65535
  const int half = (FEAT * KDIM) / 4;             // 32768
  const float* src = (i < half) ? wl : wr;
  const int j = (i < half) ? i : (i - half);
  const float4 v = ((const float4*)src)[j];
  uint2 u = make_uint2(pk2bf(v.x, v.y), pk2bf(v.z, v.w));
  ((uint2*)wbf)[i] = u;
  for (int k = i; k < 2 * N_NODES; k += 65536) z[k] = 0u;  // cnt + wc
}

// ---- CSR build: histogram of dst --------------------------------------------
__global__ __launch_bounds__(256) void hist(
    const int* __restrict__ edges, unsigned int* __restrict__ cnt)
{
  const int e = blockIdx.x * 256 + threadIdx.x;   // grid = 3125 exact
  atomicAdd(&cnt[edges[N_EDGES + e]], 1u);
}

// ---- scan stage A: per-1024-chunk sums --------------------------------------
__global__ __launch_bounds__(256) void scan_a(
    const unsigned int* __restrict__ cnt, unsigned int* __restrict__ partial)
{
  __shared__ unsigned int s[256];
  const int t = threadIdx.x;
  const int base = blockIdx.x * 1024 + t * 4;
  unsigned int sum = 0;
  #pragma unroll
  for (int j = 0; j < 4; j++) sum += (base + j < N_NODES) ? cnt[base + j] : 0u;
  s[t] = sum; __syncthreads();
  for (int off = 128; off > 0; off >>= 1) {
    if (t < off) s[t] += s[t + off];
    __syncthreads();
  }
  if (t == 0) partial[blockIdx.x] = s[0];
}

// ---- scan stage B: exclusive scan of 69 chunk sums (1 block) ----------------
__global__ __launch_bounds__(128) void scan_b(
    const unsigned int* __restrict__ partial, unsigned int* __restrict__ chunk_off)
{
  __shared__ unsigned int s[128];
  const int t = threadIdx.x;
  const unsigned int own = (t < NCHUNK) ? partial[t] : 0u;
  s[t] = own; __syncthreads();
  for (int off = 1; off < 128; off <<= 1) {
    unsigned int x = (t >= off) ? s[t - off] : 0u;
    __syncthreads();
    s[t] += x;
    __syncthreads();
  }
  if (t < NCHUNK) chunk_off[t] = s[t] - own;
}

// ---- scan stage C: row_start = chunk_off + in-chunk exclusive scan ----------
__global__ __launch_bounds__(256) void scan_c(
    const unsigned int* __restrict__ cnt, const unsigned int* __restrict__ chunk_off,
    unsigned int* __restrict__ row_start)
{
  __shared__ unsigned int s[256];
  const int t = threadIdx.x;
  const int base = blockIdx.x * 1024 + t * 4;
  unsigned int v[4], sum = 0;
  #pragma unroll
  for (int j = 0; j < 4; j++) { v[j] = (base + j < N_NODES) ? cnt[base + j] : 0u; sum += v[j]; }
  s[t] = sum; __syncthreads();
  for (int off = 1; off < 256; off <<= 1) {      // Hillis-Steele inclusive
    unsigned int x = (t >= off) ? s[t - off] : 0u;
    __syncthreads();
    s[t] += x;
    __syncthreads();
  }
  unsigned int run = chunk_off[blockIdx.x] + (s[t] - sum);
  #pragma unroll
  for (int j = 0; j < 4; j++) {
    if (base + j < N_NODES) row_start[base + j] = run;
    run += v[j];
  }
}

// ---- CSR fill: col[row_start[dst] + slot] = src ------------------------------
__global__ __launch_bounds__(256) void fill_csr(
    const int* __restrict__ edges, const unsigned int* __restrict__ row_start,
    unsigned int* __restrict__ wc, int* __restrict__ col)
{
  const int e = blockIdx.x * 256 + threadIdx.x;   // grid = 3125 exact
  const int src = edges[e];
  const int dst = edges[N_EDGES + e];
  const unsigned int pos = row_start[dst] + atomicAdd(&wc[dst], 1u);
  col[pos] = src;
}

// ---- y[m, 0:256] = feat[m, 0:1024] @ [Wl;Wr]^T (bf16 MFMA, 96x256 tile) -----
__global__ __launch_bounds__(256, 3) void gemm_sage(
    const float* __restrict__ feat,
    const unsigned short* __restrict__ wbf,
    unsigned short* __restrict__ y)
{
  __shared__ __align__(16) unsigned short As[TM][72];   // +8 pad: 144B stride
  __shared__ __align__(16) unsigned short Bs[256][72];

  const int tid  = threadIdx.x;
  const int lane = tid & 63;
  const int wid  = tid >> 6;
  const int wm   = (wid & 1) * 48;       // wave tile: 48 x 128
  const int wn   = (wid >> 1) * 128;
  const int m0   = blockIdx.x * TM;

  f32x4 acc[3][8];
  const f32x4 zero = {0.f, 0.f, 0.f, 0.f};
  #pragma unroll
  for (int i = 0; i < 3; i++)
    #pragma unroll
    for (int j = 0; j < 8; j++) acc[i][j] = zero;

  const int c4  = tid & 15;   // A col group (4 floats)
  const int r0  = tid >> 4;   // A row base (16 rows/iter)
  const int c8  = tid & 7;    // B col group (8 bf16)
  const int r0b = tid >> 3;   // B row base (32 rows/iter)

  for (int kk = 0; kk < KDIM; kk += 64) {
    // stage A: 96x64 fp32 -> bf16 (packed convert)
    #pragma unroll
    for (int i = 0; i < 6; i++) {
      int r = r0 + 16 * i;
      int m = m0 + r; if (m >= N_NODES) m = N_NODES - 1;   // clamp; not stored
      const float4 v = *(const float4*)(feat + (size_t)m * ROWLEN + kk + c4 * 4);
      uint2 u = make_uint2(pk2bf(v.x, v.y), pk2bf(v.z, v.w));
      *(uint2*)&As[r][c4 * 4] = u;
    }
    // stage B: 256x64 bf16 (pre-converted, L2-resident)
    #pragma unroll
    for (int i = 0; i < 8; i++) {
      int r = r0b + 32 * i;
      const uint4 v = *(const uint4*)(wbf + (size_t)r * KDIM + kk + c8 * 8);
      *(uint4*)&Bs[r][c8 * 8] = v;
    }
    __syncthreads();
    #pragma unroll
    for (int s = 0; s < 2; s++) {
      const int colk = s * 32 + (lane >> 4) * 8;  // frag: k = quad*8+j
      const int row  = lane & 15;
      short8 a[3];
      #pragma unroll
      for (int t = 0; t < 3; t++) a[t] = *(const short8*)&As[wm + t * 16 + row][colk];
      #pragma unroll
      for (int j = 0; j < 8; j++) {
        const short8 b = *(const short8*)&Bs[wn + j * 16 + row][colk];
        #pragma unroll
        for (int t = 0; t < 3; t++)
          acc[t][j] = __builtin_amdgcn_mfma_f32_16x16x32_bf16(a[t], b, acc[t][j], 0, 0, 0);
      }
    }
    __syncthreads();
  }

  // C/D layout: n = lane&15, m = (lane>>4)*4 + reg   [m89-verified]
  const int mb = m0 + wm + (lane >> 4) * 4;
  const int nb = wn + (lane & 15);
  #pragma unroll
  for (int t = 0; t < 3; t++) {
    #pragma unroll
    for (int r = 0; r < 4; r++) {
      const int m = mb + t * 16 + r;
      if (m < N_NODES) {
        #pragma unroll
        for (int j = 0; j < 8; j++)
          y[(size_t)m * NOUT + nb + j * 16] = f2bf(acc[t][j][r]);
      }
    }
  }
}

// ---- fused: CSR gather mean + sage-relu + concat + fc1 + BN + fc2 -----------
__global__ __launch_bounds__(256) void gather_epilogue(
    const float* __restrict__ feat,
    const unsigned short* __restrict__ y,
    const unsigned int* __restrict__ row_start,
    const unsigned int* __restrict__ cnt,
    const int* __restrict__ col,
    const float* __restrict__ b_sage_l,
    const float* __restrict__ fc1_w, const float* __restrict__ fc1_b,
    const float* __restrict__ fc2_w, const float* __restrict__ fc2_b,
    const float* __restrict__ bn_gamma, const float* __restrict__ bn_beta,
    const float* __restrict__ bn_mean, const float* __restrict__ bn_var,
    float* __restrict__ out)
{
  __shared__ float w1t[CIN][HIDDEN + 1];  // fc1_w transposed: conflict-free j-reads
  __shared__ float vbuf[4][CIN];
  __shared__ float hbuf[4][HIDDEN + 3];
  const int tid  = threadIdx.x;
  const int lane = tid & 63;
  const int w    = tid >> 6;

  for (int i = tid; i < HIDDEN * CIN; i += 256) {
    const int j = i / CIN;
    const int c = i - j * CIN;
    w1t[c][j] = fc1_w[i];
  }
  __syncthreads();

  const int m = blockIdx.x * 4 + w;       // 70000 = 17500*4, no guard needed
  const int e0 = (int)row_start[m];
  const int n  = (int)cnt[m];

  // gather: sum of y_l[src] rows; lane covers channels 2*lane, 2*lane+1
  float s0 = 0.f, s1 = 0.f;
  int i = 0;
  for (; i + 4 <= n; i += 4) {            // 4 independent chains to hide latency
    const int sa = col[e0 + i];
    const int sb = col[e0 + i + 1];
    const int sc = col[e0 + i + 2];
    const int sd = col[e0 + i + 3];
    const unsigned int va = *(const unsigned int*)(y + (size_t)sa * NOUT + lane * 2);
    const unsigned int vb = *(const unsigned int*)(y + (size_t)sb * NOUT + lane * 2);
    const unsigned int vc = *(const unsigned int*)(y + (size_t)sc * NOUT + lane * 2);
    const unsigned int vd = *(const unsigned int*)(y + (size_t)sd * NOUT + lane * 2);
    s0 += (bf2f(va & 0xFFFFu) + bf2f(vb & 0xFFFFu)) + (bf2f(vc & 0xFFFFu) + bf2f(vd & 0xFFFFu));
    s1 += (bf2f(va >> 16)     + bf2f(vb >> 16))     + (bf2f(vc >> 16)     + bf2f(vd >> 16));
  }
  for (; i < n; i++) {
    const int sa = col[e0 + i];
    const unsigned int va = *(const unsigned int*)(y + (size_t)sa * NOUT + lane * 2);
    s0 += bf2f(va & 0xFFFFu);
    s1 += bf2f(va >> 16);
  }

  const float inv = 1.0f / fmaxf((float)n, 1.0f);
  const unsigned int vr = *(const unsigned int*)(y + (size_t)m * NOUT + FEAT + lane * 2);
  vbuf[w][2 * lane]     = fmaxf(s0 * inv + b_sage_l[2 * lane]     + bf2f(vr & 0xFFFFu), 0.0f);
  vbuf[w][2 * lane + 1] = fmaxf(s1 * inv + b_sage_l[2 * lane + 1] + bf2f(vr >> 16),     0.0f);
  if (lane < CIN - FEAT)
    vbuf[w][FEAT + lane] = feat[(size_t)m * ROWLEN + KDIM + lane];  // extra 20 (no relu)
  __syncthreads();

  if (lane < HIDDEN) {
    float h = fc1_b[lane];
    #pragma unroll 4
    for (int c = 0; c < CIN; c++) h += w1t[c][lane] * vbuf[w][c];
    h = fmaxf(h, 0.0f);
    h = (h - bn_mean[lane]) * rsqrtf(bn_var[lane] + 1e-5f) * bn_gamma[lane] + bn_beta[lane];
    hbuf[w][lane] = h;
  }
  __syncthreads();

  if (lane < 3) {
    float o = fc2_b[lane];
    #pragma unroll
    for (int j = 0; j < HIDDEN; j++) o += fc2_w[lane * HIDDEN + j] * hbuf[w][j];
    out[(size_t)m * 3 + lane] = o;
  }
}

// ---- workspace layout (~40.4 MB) --------------------------------------------
#define Y_OFF    0u
#define Y_BYTES  (N_NODES * NOUT * 2u)            // 35,840,000
#define WBF_OFF  Y_BYTES                          // 35,840,000 (16-aligned)
#define WBF_BYTES (NOUT * KDIM * 2u)              //    524,288
#define CNT_OFF  (WBF_OFF + WBF_BYTES)            // 36,364,288 (16-aligned)
#define CNT_BYTES (N_NODES * 4u)                  //    280,000
#define WC_OFF   (CNT_OFF + CNT_BYTES)            // 36,644,288  (contiguous w/ cnt!)
#define RS_OFF   (WC_OFF + CNT_BYTES)             // 36,924,288
#define PART_OFF (RS_OFF + CNT_BYTES)             // 37,204,288
#define COFF_OFF (PART_OFF + 512u)                // 37,204,800
#define COL_OFF  (COFF_OFF + 512u)                // 37,205,312
#define COL_BYTES (N_EDGES * 4u)                  //  3,200,000

extern "C" void kernel_launch(void* const* d_in, const int* in_sizes, int n_in,
                              void* d_out, int out_size, void* d_ws, size_t ws_size,
                              hipStream_t stream) {
  const float* feat     = (const float*)d_in[0];
  const int*   edges    = (const int*)  d_in[1];
  // d_in[2] (edges2), d_in[3] (edge_features): unused by the reference
  const float* w_sage_l = (const float*)d_in[4];
  const float* b_sage_l = (const float*)d_in[5];
  const float* w_sage_r = (const float*)d_in[6];
  const float* fc1_w    = (const float*)d_in[7];
  const float* fc1_b    = (const float*)d_in[8];
  const float* fc2_w    = (const float*)d_in[9];
  const float* fc2_b    = (const float*)d_in[10];
  const float* bn_gamma = (const float*)d_in[11];
  const float* bn_beta  = (const float*)d_in[12];
  const float* bn_mean  = (const float*)d_in[13];
  const float* bn_var   = (const float*)d_in[14];
  float* out = (float*)d_out;

  char* ws = (char*)d_ws;
  unsigned short* y    = (unsigned short*)(ws + Y_OFF);
  unsigned short* wbf  = (unsigned short*)(ws + WBF_OFF);
  unsigned int*   cnt  = (unsigned int*)(ws + CNT_OFF);
  unsigned int*   wc   = (unsigned int*)(ws + WC_OFF);
  unsigned int*   rs   = (unsigned int*)(ws + RS_OFF);
  unsigned int*   part = (unsigned int*)(ws + PART_OFF);
  unsigned int*   coff = (unsigned int*)(ws + COFF_OFF);
  int*            col  = (int*)(ws + COL_OFF);

  cvt_w<<<256, 256, 0, stream>>>(w_sage_l, w_sage_r, wbf, cnt);  // also zeros cnt+wc
  hist<<<N_EDGES / 256, 256, 0, stream>>>(edges, cnt);
  scan_a<<<NCHUNK, 256, 0, stream>>>(cnt, part);
  scan_b<<<1, 128, 0, stream>>>(part, coff);
  scan_c<<<NCHUNK, 256, 0, stream>>>(cnt, coff, rs);
  fill_csr<<<N_EDGES / 256, 256, 0, stream>>>(edges, rs, wc, col);
  gemm_sage<<<(N_NODES + TM - 1) / TM, 256, 0, stream>>>(feat, wbf, y);
  gather_epilogue<<<N_NODES / 4, 256, 0, stream>>>(feat, y, rs, cnt, col, b_sage_l,
                                                   fc1_w, fc1_b, fc2_w, fc2_b,
                                                   bn_gamma, bn_beta, bn_mean, bn_var, out);
}